// Round 17
// baseline (141.450 us; speedup 1.0000x reference)
//
#include <hip/hip_runtime.h>
#include <cstdint>
#include <math.h>

typedef __attribute__((ext_vector_type(8))) short short8;
typedef __attribute__((ext_vector_type(4))) float f32x4;

#define LOG2E 1.44269504088896340736f

static __device__ __forceinline__ float bf2f(unsigned short u) {
    union { unsigned int i; float f; } v; v.i = ((unsigned int)u) << 16; return v.f;
}
static __device__ __forceinline__ unsigned short f2bf(float f) {
    union { float f; unsigned int i; } v; v.f = f;
    unsigned int r = v.i + 0x7FFF + ((v.i >> 16) & 1);
    return (unsigned short)(r >> 16);
}

// ---------------- K1: fused prep = bias(1088 blocks first) + convert(6144) ----
// (unchanged from round 15 — validated; bias in swapped-QK C-layout)
__global__ __launch_bounds__(256) void k_prep(
    const float* __restrict__ x, const float* __restrict__ wq,
    const float* __restrict__ wk, const float* __restrict__ wv,
    const float* __restrict__ wo, unsigned short* __restrict__ dstconv,
    const float* __restrict__ Eidx, const float* __restrict__ Ebar,
    const float* __restrict__ Epos, const float* __restrict__ Eoct,
    const float* __restrict__ Esemi,
    const int* __restrict__ barm, const int* __restrict__ posm,
    const int* __restrict__ octm, const int* __restrict__ semim,
    unsigned short* __restrict__ biasg) {
    __shared__ float2 t2[8 * 233];
    __shared__ int    pk[16 * 65];

    if (blockIdx.x >= 1088) {
        long t = (long)(blockIdx.x - 1088) * 256 + threadIdx.x;
        long base = t * 4;
        const long NX = 2097152, NW = 1048576;
        const float* src; long off;
        if (base < NX)            { src = x;  off = base; }
        else if (base < NX + NW)  { src = wq; off = base - NX; }
        else if (base < NX + 2*NW){ src = wk; off = base - NX - NW; }
        else if (base < NX + 3*NW){ src = wv; off = base - NX - 2*NW; }
        else                      { src = wo; off = base - NX - 3*NW; }
        float4 v = *(const float4*)(src + off);
        ushort4 o;
        o.x = f2bf(v.x); o.y = f2bf(v.y); o.z = f2bf(v.z); o.w = f2bf(v.w);
        *(ushort4*)(dstconv + base) = o;
        return;
    }
    int fid = blockIdx.x;
    int b = (fid >= 544) ? 1 : 0;
    int f = fid - b * 544;
    int ti, tj;
    if (f >= 480) { int rr = f - 480; ti = 60 + (rr >> 4); tj = rr & 15; }
    else {
        int g = (int)(0.5f * (sqrtf(1.0f + 2.0f * (float)f) - 1.0f));
        while (2 * (g + 1) * (g + 2) <= f) g++;
        while (2 * g * (g + 1) > f) g--;
        int rr = f - 2 * g * (g + 1);
        int q = rr / (g + 1);
        ti = g * 4 + q;
        tj = rr - q * (g + 1);
    }
    int i0 = ti * 16, j0 = tj * 64;

    int t = threadIdx.x;
    int rel_lo = i0 - j0 - 63; if (rel_lo < 0) rel_lo = 0;

    for (int idx = t; idx < 231 * 8; idx += 256) {
        int s = idx >> 3, h2 = idx & 7;
        float va, vb;
        if (s < 80) {
            int src = rel_lo + s; if (src > 1023) src = 1023;
            va = Eidx[src * 16 + h2]; vb = Eidx[src * 16 + h2 + 8];
        } else if (s < 97)  { va = Ebar[(s - 80) * 16 + h2];  vb = Ebar[(s - 80) * 16 + h2 + 8]; }
        else if (s < 193)   { va = Epos[(s - 97) * 16 + h2];  vb = Epos[(s - 97) * 16 + h2 + 8]; }
        else if (s < 218)   { va = Eoct[(s - 193) * 16 + h2]; vb = Eoct[(s - 193) * 16 + h2 + 8]; }
        else                { va = Esemi[(s - 218) * 16 + h2]; vb = Esemi[(s - 218) * 16 + h2 + 8]; }
        t2[h2 * 233 + s] = make_float2(va, vb);
    }
    #pragma unroll
    for (int cc = 0; cc < 4; cc++) {
        int cell = t + cc * 256;
        int i = i0 + (cell >> 6), j = j0 + (cell & 63);
        long ij = ((long)b << 20) + ((long)i << 10) + j;
        int v = (barm[ij] + 1) | ((posm[ij] + 1) << 5) |
                ((octm[ij] + 1) << 12) | ((semim[ij] + 1) << 17);
        pk[(cell >> 6) * 65 + (cell & 63)] = v;
    }
    __syncthreads();

    int lane = t & 63, q = t & 15, G = (t >> 4) & 3, hq = t >> 6;
    int base_rel = (i0 + q) - j0 - rel_lo;
    const float2* TA = &t2[hq * 233];
    const float2* TB = &t2[(hq + 4) * 233];
    long tbase = ((((long)(b * 16) * 64 + ti) * 16 + tj) << 10) + lane * 16;
    #pragma unroll
    for (int sub = 0; sub < 4; sub++) {
        ushort4 o0, o1, o2, o3;
        #pragma unroll
        for (int rr = 0; rr < 4; rr++) {
            int key = sub * 16 + G * 4 + rr;
            int p = pk[q * 65 + key];
            int sr = base_rel - key; if (sr < 0) sr = 0;
            float2 a0 = TA[sr];
            float2 a1 = TA[80  + (p & 31)];
            float2 a2 = TA[97  + ((p >> 5)  & 127)];
            float2 a3 = TA[193 + ((p >> 12) & 31)];
            float2 a4 = TA[218 + ((p >> 17) & 15)];
            float2 b0 = TB[sr];
            float2 b1 = TB[80  + (p & 31)];
            float2 b2 = TB[97  + ((p >> 5)  & 127)];
            float2 b3 = TB[193 + ((p >> 12) & 31)];
            float2 b4 = TB[218 + ((p >> 17) & 15)];
            float xA = a0.x + a1.x + a2.x + a3.x + a4.x;
            float yA = a0.y + a1.y + a2.y + a3.y + a4.y;
            float xB = b0.x + b1.x + b2.x + b3.x + b4.x;
            float yB = b0.y + b1.y + b2.y + b3.y + b4.y;
            ((unsigned short*)&o0)[rr] = f2bf(xA * 0.125f);
            ((unsigned short*)&o1)[rr] = f2bf(xB * 0.125f);
            ((unsigned short*)&o2)[rr] = f2bf(yA * 0.125f);
            ((unsigned short*)&o3)[rr] = f2bf(yB * 0.125f);
        }
        *(ushort4*)(biasg + tbase + ((long)hq        << 20) + sub * 4) = o0;
        *(ushort4*)(biasg + tbase + ((long)(hq + 4)  << 20) + sub * 4) = o1;
        *(ushort4*)(biasg + tbase + ((long)(hq + 8)  << 20) + sub * 4) = o2;
        *(ushort4*)(biasg + tbase + ((long)(hq + 12) << 20) + sub * 4) = o3;
    }
}

// ---------------- K3/K5: bf16 GEMM, 128x64 tile, global_load_lds --------------
// (unchanged from round 13/14 — validated)
__global__ __launch_bounds__(256) void k_gemm(
    const unsigned short* __restrict__ A,
    const unsigned short* __restrict__ B0, const unsigned short* __restrict__ B1,
    const unsigned short* __restrict__ B2,
    unsigned short* __restrict__ qd, unsigned short* __restrict__ kd,
    unsigned short* __restrict__ vtd, float* __restrict__ outf, int mode) {
    __shared__ unsigned short As[128 * 64];
    __shared__ unsigned short Bs[64 * 64];
    int md = (mode < 0) ? (int)blockIdx.z : mode;
    const unsigned short* B = (md == 1) ? B1 : (md == 2) ? B2 : B0;
    int m0 = blockIdx.x * 128, n0 = blockIdx.y * 64;
    int t = threadIdx.x;
    int w = t >> 6, lane = t & 63, g = lane >> 4, c = lane & 15;
    int wr = w >> 1, wc = w & 1;
    const int K = 1024;
    f32x4 zero = {0.f, 0.f, 0.f, 0.f};
    f32x4 acc[4][2];
    #pragma unroll
    for (int m = 0; m < 4; m++)
        #pragma unroll
        for (int n = 0; n < 2; n++) acc[m][n] = zero;

    int srow = w * 8 + (lane >> 3);
    int scol = (lane & 7) * 8;
    for (int k0 = 0; k0 < K; k0 += 64) {
        __syncthreads();
        #pragma unroll
        for (int qq = 0; qq < 4; qq++) {
            int row = qq * 32 + srow;
            __builtin_amdgcn_global_load_lds(
                (const __attribute__((address_space(1))) unsigned int*)(A + (long)(m0 + row) * K + k0 + scol),
                (__attribute__((address_space(3))) unsigned int*)&As[(qq * 32 + w * 8) * 64],
                16, 0, 0);
        }
        #pragma unroll
        for (int qq = 0; qq < 2; qq++) {
            int row = qq * 32 + srow;
            __builtin_amdgcn_global_load_lds(
                (const __attribute__((address_space(1))) unsigned int*)(B + (long)(n0 + row) * K + k0 + scol),
                (__attribute__((address_space(3))) unsigned int*)&Bs[(qq * 32 + w * 8) * 64],
                16, 0, 0);
        }
        __syncthreads();
        #pragma unroll
        for (int kk = 0; kk < 2; kk++) {
            short8 a[4], bb[2];
            #pragma unroll
            for (int m = 0; m < 4; m++)
                a[m] = *(const short8*)&As[(wr * 64 + m * 16 + c) * 64 + kk * 32 + g * 8];
            #pragma unroll
            for (int n = 0; n < 2; n++)
                bb[n] = *(const short8*)&Bs[(wc * 32 + n * 16 + c) * 64 + kk * 32 + g * 8];
            #pragma unroll
            for (int m = 0; m < 4; m++)
                #pragma unroll
                for (int n = 0; n < 2; n++)
                    acc[m][n] = __builtin_amdgcn_mfma_f32_16x16x32_bf16(a[m], bb[n], acc[m][n], 0, 0, 0);
        }
    }

    if (md <= 1) {
        unsigned short* dst = (md == 0) ? qd : kd;
        float scale = (md == 0) ? 0.125f : 1.0f;
        #pragma unroll
        for (int m = 0; m < 4; m++) {
            #pragma unroll
            for (int r = 0; r < 4; r++) {
                int mm = m0 + wr * 64 + m * 16 + g * 4 + r;
                int bb2 = mm >> 10, ii = mm & 1023;
                #pragma unroll
                for (int n = 0; n < 2; n++) {
                    int nn = n0 + wc * 32 + n * 16 + c;
                    int hh = nn >> 6, dd = nn & 63;
                    dst[(((long)(bb2 * 16 + hh) << 10) + ii) * 64 + dd] = f2bf(acc[m][n][r] * scale);
                }
            }
        }
    } else if (md == 2) {
        #pragma unroll
        for (int m = 0; m < 4; m++) {
            int mm0 = m0 + wr * 64 + m * 16 + g * 4;
            int bb2 = mm0 >> 10, ii = mm0 & 1023;
            #pragma unroll
            for (int n = 0; n < 2; n++) {
                int nn = n0 + wc * 32 + n * 16 + c;
                int hh = nn >> 6, dd = nn & 63;
                ushort4 pkv;
                pkv.x = f2bf(acc[m][n][0]); pkv.y = f2bf(acc[m][n][1]);
                pkv.z = f2bf(acc[m][n][2]); pkv.w = f2bf(acc[m][n][3]);
                *(ushort4*)&vtd[(((long)(bb2 * 16 + hh) << 6) + dd) * 1024 + ii] = pkv;
            }
        }
    } else {
        #pragma unroll
        for (int m = 0; m < 4; m++) {
            #pragma unroll
            for (int r = 0; r < 4; r++) {
                long mm = m0 + wr * 64 + m * 16 + g * 4 + r;
                #pragma unroll
                for (int n = 0; n < 2; n++) {
                    int nn = n0 + wc * 32 + n * 16 + c;
                    outf[mm * 1024 + nn] = acc[m][n][r];
                }
            }
        }
    }
}

// ---------------- K4: flash attention, swapped-QK, stripe-paired --------------
// grid 1024 = 32 pairs x 32 (b,h): block runs stripes {63-pid (heavy), pid
// (light)} = uniform ~17 j-tile units -> 4 blocks/CU, one residency round,
// near-zero drain. Tile loop NOT unrolled (#pragma unroll 1) + launch_bounds
// (256,4) caps VGPR<=128 so 4 waves/SIMD residency is guaranteed.
#define LOADT(KA, KB, BV, JT) do {                                             \
    int _j0 = (JT) * 64;                                                       \
    _Pragma("unroll")                                                          \
    for (int _s = 0; _s < 4; _s++) {                                           \
        const unsigned short* _kr = Kp + (long)(_j0 + _s * 16 + c) * 64 + g * 8; \
        KA[_s] = *(const short8*)(_kr);                                        \
        KB[_s] = *(const short8*)(_kr + 32);                                   \
    }                                                                          \
    const unsigned short* _bp = Bt + ((JT) << 10) + lane * 16;                 \
    BV[0] = *(const short8*)(_bp);                                             \
    BV[1] = *(const short8*)(_bp + 8);                                         \
} while (0)

#define BODY(KA, KB, BV, JT) do {                                             \
    int _j0 = (JT) * 64;                                                      \
    f32x4 _s[4];                                                              \
    _Pragma("unroll")                                                         \
    for (int _sub = 0; _sub < 4; _sub++) {                                    \
        _s[_sub] = __builtin_amdgcn_mfma_f32_16x16x32_bf16(KA[_sub], q0, zero, 0, 0, 0); \
        _s[_sub] = __builtin_amdgcn_mfma_f32_16x16x32_bf16(KB[_sub], q1, _s[_sub], 0, 0, 0); \
    }                                                                         \
    short8 _v0[4], _v1[4];                                                    \
    _Pragma("unroll")                                                         \
    for (int _dd = 0; _dd < 4; _dd++) {                                       \
        const unsigned short* _vb = Vp + (long)(_dd * 16 + c) * 1024 + _j0 + g * 8; \
        _v0[_dd] = *(const short8*)(_vb);                                     \
        _v1[_dd] = *(const short8*)(_vb + 32);                                \
    }                                                                         \
    unsigned int _P0[4], _P1[4];                                              \
    _Pragma("unroll")                                                         \
    for (int _sub = 0; _sub < 4; _sub++) {                                    \
        float _pe[4];                                                         \
        _Pragma("unroll")                                                     \
        for (int _r = 0; _r < 4; _r++) {                                      \
            int _idx = _sub * 4 + _r;                                         \
            float _ss = _s[_sub][_r] +                                        \
                ((_idx < 8) ? bf2f((unsigned short)BV[0][_idx])               \
                            : bf2f((unsigned short)BV[1][_idx - 8]));         \
            if ((JT) == nj - 1 && _j0 + _sub * 16 + g * 4 + _r > i0 + c)      \
                _ss = -1e9f;                                                  \
            _pe[_r] = exp2f(__builtin_fmaf(_ss, LOG2E, -8.0f * LOG2E));       \
            l += _pe[_r];                                                     \
        }                                                                     \
        asm("v_cvt_pk_bf16_f32 %0, %1, %2" : "=v"(_P0[_sub]) : "v"(_pe[0]), "v"(_pe[1])); \
        asm("v_cvt_pk_bf16_f32 %0, %1, %2" : "=v"(_P1[_sub]) : "v"(_pe[2]), "v"(_pe[3])); \
    }                                                                         \
    _Pragma("unroll")                                                         \
    for (int _ch = 0; _ch < 2; _ch++) {                                       \
        unsigned int _a0 = (unsigned int)__shfl((int)_P0[_ch * 2],     srcA); \
        unsigned int _a1 = (unsigned int)__shfl((int)_P0[_ch * 2 + 1], srcA); \
        unsigned int _b0 = (unsigned int)__shfl((int)_P1[_ch * 2],     srcA); \
        unsigned int _b1 = (unsigned int)__shfl((int)_P1[_ch * 2 + 1], srcA); \
        unsigned int _c0 = (unsigned int)__shfl((int)_P0[_ch * 2],     srcB); \
        unsigned int _c1 = (unsigned int)__shfl((int)_P0[_ch * 2 + 1], srcB); \
        unsigned int _d0 = (unsigned int)__shfl((int)_P1[_ch * 2],     srcB); \
        unsigned int _d1 = (unsigned int)__shfl((int)_P1[_ch * 2 + 1], srcB); \
        union { unsigned int u[4]; short8 s8; } _pb;                          \
        _pb.u[0] = sel ? _a1 : _a0;                                           \
        _pb.u[1] = sel ? _b1 : _b0;                                           \
        _pb.u[2] = sel ? _c1 : _c0;                                           \
        _pb.u[3] = sel ? _d1 : _d0;                                           \
        _Pragma("unroll")                                                     \
        for (int _dd = 0; _dd < 4; _dd++)                                     \
            o[_dd] = __builtin_amdgcn_mfma_f32_16x16x32_bf16(                 \
                (_ch == 0) ? _v0[_dd] : _v1[_dd], _pb.s8, o[_dd], 0, 0, 0);   \
    }                                                                         \
} while (0)

__global__ __launch_bounds__(256, 4) void k_attn(
    const unsigned short* __restrict__ Qs, const unsigned short* __restrict__ Ks,
    const unsigned short* __restrict__ VTs, const unsigned short* __restrict__ biasg,
    unsigned short* __restrict__ Os) {
    // per-wave 4672B: oc 64x17 f32 [0,4352) + lc 64 f32 [4352,4608) + pad
    __shared__ char smem[4 * 4672];
    int bid = blockIdx.x;
    int pid = bid >> 5;                 // 0..31 stripe pair
    int bh = bid & 31;
    int b = bh >> 4, h = bh & 15;
    int w = threadIdx.x >> 6;
    int lane = threadIdx.x & 63;
    int g = lane >> 4, c = lane & 15;
    int srcA = ((lane >> 4) & 1) * 32 + c;   // P-exchange sources
    int srcB = srcA + 16;
    int sel  = (lane >> 5) & 1;

    char* wbase = smem + w * 4672;

    long plane = ((long)bh) << 16;
    const unsigned short* Qp = Qs + plane;
    const unsigned short* Kp = Ks + plane;
    const unsigned short* Vp = VTs + plane;             // [64 d][1024 j]

    f32x4 zero = {0.f, 0.f, 0.f, 0.f};

    #pragma unroll 1
    for (int tile = 0; tile < 2; tile++) {
        int it = tile ? pid : (63 - pid);               // heavy first
        int i0 = it * 16;
        const unsigned short* Bt = biasg + (((long)bh * 64 + it) << 14);

        short8 q0 = *(const short8*)(Qp + (long)(i0 + c) * 64 + g * 8);
        short8 q1 = *(const short8*)(Qp + (long)(i0 + c) * 64 + 32 + g * 8);

        f32x4 o[4]; o[0] = zero; o[1] = zero; o[2] = zero; o[3] = zero;
        float l = 0.f;

        int nj = (it >> 2) + 1;        // 64-col tiles
        short8 kaA[4], kbA[4], bvA[2];
        short8 kaB[4], kbB[4], bvB[2];
        if (w < nj) LOADT(kaA, kbA, bvA, w);
        for (int jt = w; jt < nj; jt += 8) {
            if (jt + 4 < nj) LOADT(kaB, kbB, bvB, jt + 4);
            BODY(kaA, kbA, bvA, jt);
            if (jt + 4 < nj) {
                if (jt + 8 < nj) LOADT(kaA, kbA, bvA, jt + 8);
                BODY(kaB, kbB, bvB, jt + 4);
            }
        }
        // ---- cross-wave combine: plain sums ----
        float* oc = (float*)wbase;                 // [64][17]
        float* lc = (float*)(wbase + 4352);        // [64]
        #pragma unroll
        for (int db = 0; db < 4; db++)
            #pragma unroll
            for (int r = 0; r < 4; r++)
                oc[lane * 17 + db * 4 + r] = o[db][r];
        lc[lane] = l;
        __syncthreads();

        {
            int db = w;                             // wave w stores d-block w
            float lv = 0.f;
            #pragma unroll
            for (int ww = 0; ww < 4; ww++)
                lv += ((const float*)(smem + ww * 4672 + 4352))[lane];
            lv += __shfl_xor(lv, 16);
            lv += __shfl_xor(lv, 32);
            float linv = 1.0f / lv;
            float ov[4];
            #pragma unroll
            for (int r = 0; r < 4; r++) {
                float s = 0.f;
                #pragma unroll
                for (int ww = 0; ww < 4; ww++)
                    s += ((const float*)(smem + ww * 4672))[lane * 17 + db * 4 + r];
                ov[r] = s;
            }
            int i = i0 + c;
            unsigned short* op = Os + ((long)(b * 1024 + i)) * 1024 + h * 64 + db * 16 + g * 4;
            ushort4 o4;
            o4.x = f2bf(ov[0] * linv); o4.y = f2bf(ov[1] * linv);
            o4.z = f2bf(ov[2] * linv); o4.w = f2bf(ov[3] * linv);
            *(ushort4*)op = o4;
        }
        __syncthreads();   // protect smem overlay before next tile
    }
}

// ------------------------------- launch ---------------------------------------
extern "C" void kernel_launch(void* const* d_in, const int* in_sizes, int n_in,
                              void* d_out, int out_size, void* d_ws, size_t ws_size,
                              hipStream_t stream) {
    const float* x     = (const float*)d_in[0];
    const float* Wq    = (const float*)d_in[1];
    const float* Wk    = (const float*)d_in[2];
    const float* Wv    = (const float*)d_in[3];
    const float* Wo    = (const float*)d_in[4];
    const float* Eidx  = (const float*)d_in[5];
    const float* Ebar  = (const float*)d_in[6];
    const float* Epos  = (const float*)d_in[7];
    const float* Eoct  = (const float*)d_in[8];
    const float* Esemi = (const float*)d_in[9];
    const int* barm    = (const int*)d_in[10];
    const int* posm    = (const int*)d_in[11];
    const int* octm    = (const int*)d_in[12];
    const int* semim   = (const int*)d_in[13];
    float* outf = (float*)d_out;

    unsigned short* w = (unsigned short*)d_ws;
    unsigned short* XB   = w;                   // 2M el
    unsigned short* WQB  = w + 2097152;         // 1M el each
    unsigned short* WKB  = w + 3145728;
    unsigned short* WVB  = w + 4194304;
    unsigned short* WOB  = w + 5242880;
    unsigned short* QS   = w + 6291456;         // (b,h,n,d)
    unsigned short* KS   = w + 8388608;
    unsigned short* VTS  = w + 10485760;        // (b,h,d,n)
    unsigned short* OS   = w + 12582912;        // (b,n,h*d)
    unsigned short* BIAS = w + 14680064;        // 32M el, swapped frag tiles

    k_prep<<<7232, 256, 0, stream>>>(x, Wq, Wk, Wv, Wo, w,
                                     Eidx, Ebar, Epos, Eoct, Esemi,
                                     barm, posm, octm, semim, BIAS);
    k_gemm<<<dim3(16, 16, 3), 256, 0, stream>>>(XB, WQB, WKB, WVB,
                                                QS, KS, VTS, nullptr, -1);
    k_attn<<<1024, 256, 0, stream>>>(QS, KS, VTS, BIAS, OS);
    k_gemm<<<dim3(16, 16, 1), 256, 0, stream>>>(OS, WOB, WOB, WOB,
                                                QS, KS, VTS, outf, 3);
}

// Round 21
// 103.249 us; speedup vs baseline: 1.3700x; 1.3700x over previous
//
#include <hip/hip_runtime.h>
#include <cstdint>
#include <math.h>

typedef __attribute__((ext_vector_type(8))) short short8;
typedef __attribute__((ext_vector_type(4))) float f32x4;

#define LOG2E 1.44269504088896340736f

static __device__ __forceinline__ float bf2f(unsigned short u) {
    union { unsigned int i; float f; } v; v.i = ((unsigned int)u) << 16; return v.f;
}
static __device__ __forceinline__ unsigned short f2bf(float f) {
    union { float f; unsigned int i; } v; v.f = f;
    unsigned int r = v.i + 0x7FFF + ((v.i >> 16) & 1);
    return (unsigned short)(r >> 16);
}

// ---------------- K1: fused prep = bias(1088 blocks first) + convert(6144) ----
// (unchanged from round 15 — validated; bias in swapped-QK C-layout)
__global__ __launch_bounds__(256) void k_prep(
    const float* __restrict__ x, const float* __restrict__ wq,
    const float* __restrict__ wk, const float* __restrict__ wv,
    const float* __restrict__ wo, unsigned short* __restrict__ dstconv,
    const float* __restrict__ Eidx, const float* __restrict__ Ebar,
    const float* __restrict__ Epos, const float* __restrict__ Eoct,
    const float* __restrict__ Esemi,
    const int* __restrict__ barm, const int* __restrict__ posm,
    const int* __restrict__ octm, const int* __restrict__ semim,
    unsigned short* __restrict__ biasg) {
    __shared__ float2 t2[8 * 233];
    __shared__ int    pk[16 * 65];

    if (blockIdx.x >= 1088) {
        long t = (long)(blockIdx.x - 1088) * 256 + threadIdx.x;
        long base = t * 4;
        const long NX = 2097152, NW = 1048576;
        const float* src; long off;
        if (base < NX)            { src = x;  off = base; }
        else if (base < NX + NW)  { src = wq; off = base - NX; }
        else if (base < NX + 2*NW){ src = wk; off = base - NX - NW; }
        else if (base < NX + 3*NW){ src = wv; off = base - NX - 2*NW; }
        else                      { src = wo; off = base - NX - 3*NW; }
        float4 v = *(const float4*)(src + off);
        ushort4 o;
        o.x = f2bf(v.x); o.y = f2bf(v.y); o.z = f2bf(v.z); o.w = f2bf(v.w);
        *(ushort4*)(dstconv + base) = o;
        return;
    }
    int fid = blockIdx.x;
    int b = (fid >= 544) ? 1 : 0;
    int f = fid - b * 544;
    int ti, tj;
    if (f >= 480) { int rr = f - 480; ti = 60 + (rr >> 4); tj = rr & 15; }
    else {
        int g = (int)(0.5f * (sqrtf(1.0f + 2.0f * (float)f) - 1.0f));
        while (2 * (g + 1) * (g + 2) <= f) g++;
        while (2 * g * (g + 1) > f) g--;
        int rr = f - 2 * g * (g + 1);
        int q = rr / (g + 1);
        ti = g * 4 + q;
        tj = rr - q * (g + 1);
    }
    int i0 = ti * 16, j0 = tj * 64;

    int t = threadIdx.x;
    int rel_lo = i0 - j0 - 63; if (rel_lo < 0) rel_lo = 0;

    for (int idx = t; idx < 231 * 8; idx += 256) {
        int s = idx >> 3, h2 = idx & 7;
        float va, vb;
        if (s < 80) {
            int src = rel_lo + s; if (src > 1023) src = 1023;
            va = Eidx[src * 16 + h2]; vb = Eidx[src * 16 + h2 + 8];
        } else if (s < 97)  { va = Ebar[(s - 80) * 16 + h2];  vb = Ebar[(s - 80) * 16 + h2 + 8]; }
        else if (s < 193)   { va = Epos[(s - 97) * 16 + h2];  vb = Epos[(s - 97) * 16 + h2 + 8]; }
        else if (s < 218)   { va = Eoct[(s - 193) * 16 + h2]; vb = Eoct[(s - 193) * 16 + h2 + 8]; }
        else                { va = Esemi[(s - 218) * 16 + h2]; vb = Esemi[(s - 218) * 16 + h2 + 8]; }
        t2[h2 * 233 + s] = make_float2(va, vb);
    }
    #pragma unroll
    for (int cc = 0; cc < 4; cc++) {
        int cell = t + cc * 256;
        int i = i0 + (cell >> 6), j = j0 + (cell & 63);
        long ij = ((long)b << 20) + ((long)i << 10) + j;
        int v = (barm[ij] + 1) | ((posm[ij] + 1) << 5) |
                ((octm[ij] + 1) << 12) | ((semim[ij] + 1) << 17);
        pk[(cell >> 6) * 65 + (cell & 63)] = v;
    }
    __syncthreads();

    int lane = t & 63, q = t & 15, G = (t >> 4) & 3, hq = t >> 6;
    int base_rel = (i0 + q) - j0 - rel_lo;
    const float2* TA = &t2[hq * 233];
    const float2* TB = &t2[(hq + 4) * 233];
    long tbase = ((((long)(b * 16) * 64 + ti) * 16 + tj) << 10) + lane * 16;
    #pragma unroll
    for (int sub = 0; sub < 4; sub++) {
        ushort4 o0, o1, o2, o3;
        #pragma unroll
        for (int rr = 0; rr < 4; rr++) {
            int key = sub * 16 + G * 4 + rr;
            int p = pk[q * 65 + key];
            int sr = base_rel - key; if (sr < 0) sr = 0;
            float2 a0 = TA[sr];
            float2 a1 = TA[80  + (p & 31)];
            float2 a2 = TA[97  + ((p >> 5)  & 127)];
            float2 a3 = TA[193 + ((p >> 12) & 31)];
            float2 a4 = TA[218 + ((p >> 17) & 15)];
            float2 b0 = TB[sr];
            float2 b1 = TB[80  + (p & 31)];
            float2 b2 = TB[97  + ((p >> 5)  & 127)];
            float2 b3 = TB[193 + ((p >> 12) & 31)];
            float2 b4 = TB[218 + ((p >> 17) & 15)];
            float xA = a0.x + a1.x + a2.x + a3.x + a4.x;
            float yA = a0.y + a1.y + a2.y + a3.y + a4.y;
            float xB = b0.x + b1.x + b2.x + b3.x + b4.x;
            float yB = b0.y + b1.y + b2.y + b3.y + b4.y;
            ((unsigned short*)&o0)[rr] = f2bf(xA * 0.125f);
            ((unsigned short*)&o1)[rr] = f2bf(xB * 0.125f);
            ((unsigned short*)&o2)[rr] = f2bf(yA * 0.125f);
            ((unsigned short*)&o3)[rr] = f2bf(yB * 0.125f);
        }
        *(ushort4*)(biasg + tbase + ((long)hq        << 20) + sub * 4) = o0;
        *(ushort4*)(biasg + tbase + ((long)(hq + 4)  << 20) + sub * 4) = o1;
        *(ushort4*)(biasg + tbase + ((long)(hq + 8)  << 20) + sub * 4) = o2;
        *(ushort4*)(biasg + tbase + ((long)(hq + 12) << 20) + sub * 4) = o3;
    }
}

// ---------------- K3/K5: bf16 GEMM, 128x64 tile, global_load_lds --------------
// (unchanged from round 13/14 — validated)
__global__ __launch_bounds__(256) void k_gemm(
    const unsigned short* __restrict__ A,
    const unsigned short* __restrict__ B0, const unsigned short* __restrict__ B1,
    const unsigned short* __restrict__ B2,
    unsigned short* __restrict__ qd, unsigned short* __restrict__ kd,
    unsigned short* __restrict__ vtd, float* __restrict__ outf, int mode) {
    __shared__ unsigned short As[128 * 64];
    __shared__ unsigned short Bs[64 * 64];
    int md = (mode < 0) ? (int)blockIdx.z : mode;
    const unsigned short* B = (md == 1) ? B1 : (md == 2) ? B2 : B0;
    int m0 = blockIdx.x * 128, n0 = blockIdx.y * 64;
    int t = threadIdx.x;
    int w = t >> 6, lane = t & 63, g = lane >> 4, c = lane & 15;
    int wr = w >> 1, wc = w & 1;
    const int K = 1024;
    f32x4 zero = {0.f, 0.f, 0.f, 0.f};
    f32x4 acc[4][2];
    #pragma unroll
    for (int m = 0; m < 4; m++)
        #pragma unroll
        for (int n = 0; n < 2; n++) acc[m][n] = zero;

    int srow = w * 8 + (lane >> 3);
    int scol = (lane & 7) * 8;
    for (int k0 = 0; k0 < K; k0 += 64) {
        __syncthreads();
        #pragma unroll
        for (int qq = 0; qq < 4; qq++) {
            int row = qq * 32 + srow;
            __builtin_amdgcn_global_load_lds(
                (const __attribute__((address_space(1))) unsigned int*)(A + (long)(m0 + row) * K + k0 + scol),
                (__attribute__((address_space(3))) unsigned int*)&As[(qq * 32 + w * 8) * 64],
                16, 0, 0);
        }
        #pragma unroll
        for (int qq = 0; qq < 2; qq++) {
            int row = qq * 32 + srow;
            __builtin_amdgcn_global_load_lds(
                (const __attribute__((address_space(1))) unsigned int*)(B + (long)(n0 + row) * K + k0 + scol),
                (__attribute__((address_space(3))) unsigned int*)&Bs[(qq * 32 + w * 8) * 64],
                16, 0, 0);
        }
        __syncthreads();
        #pragma unroll
        for (int kk = 0; kk < 2; kk++) {
            short8 a[4], bb[2];
            #pragma unroll
            for (int m = 0; m < 4; m++)
                a[m] = *(const short8*)&As[(wr * 64 + m * 16 + c) * 64 + kk * 32 + g * 8];
            #pragma unroll
            for (int n = 0; n < 2; n++)
                bb[n] = *(const short8*)&Bs[(wc * 32 + n * 16 + c) * 64 + kk * 32 + g * 8];
            #pragma unroll
            for (int m = 0; m < 4; m++)
                #pragma unroll
                for (int n = 0; n < 2; n++)
                    acc[m][n] = __builtin_amdgcn_mfma_f32_16x16x32_bf16(a[m], bb[n], acc[m][n], 0, 0, 0);
        }
    }

    if (md <= 1) {
        unsigned short* dst = (md == 0) ? qd : kd;
        float scale = (md == 0) ? 0.125f : 1.0f;
        #pragma unroll
        for (int m = 0; m < 4; m++) {
            #pragma unroll
            for (int r = 0; r < 4; r++) {
                int mm = m0 + wr * 64 + m * 16 + g * 4 + r;
                int bb2 = mm >> 10, ii = mm & 1023;
                #pragma unroll
                for (int n = 0; n < 2; n++) {
                    int nn = n0 + wc * 32 + n * 16 + c;
                    int hh = nn >> 6, dd = nn & 63;
                    dst[(((long)(bb2 * 16 + hh) << 10) + ii) * 64 + dd] = f2bf(acc[m][n][r] * scale);
                }
            }
        }
    } else if (md == 2) {
        #pragma unroll
        for (int m = 0; m < 4; m++) {
            int mm0 = m0 + wr * 64 + m * 16 + g * 4;
            int bb2 = mm0 >> 10, ii = mm0 & 1023;
            #pragma unroll
            for (int n = 0; n < 2; n++) {
                int nn = n0 + wc * 32 + n * 16 + c;
                int hh = nn >> 6, dd = nn & 63;
                ushort4 pkv;
                pkv.x = f2bf(acc[m][n][0]); pkv.y = f2bf(acc[m][n][1]);
                pkv.z = f2bf(acc[m][n][2]); pkv.w = f2bf(acc[m][n][3]);
                *(ushort4*)&vtd[(((long)(bb2 * 16 + hh) << 6) + dd) * 1024 + ii] = pkv;
            }
        }
    } else {
        #pragma unroll
        for (int m = 0; m < 4; m++) {
            #pragma unroll
            for (int r = 0; r < 4; r++) {
                long mm = m0 + wr * 64 + m * 16 + g * 4 + r;
                #pragma unroll
                for (int n = 0; n < 2; n++) {
                    int nn = n0 + wc * 32 + n * 16 + c;
                    outf[mm * 1024 + nn] = acc[m][n][r];
                }
            }
        }
    }
}

// ---------------- K4: flash attention, swapped-QK, LDS-free P-exchange --------
// (byte-exact revert to round 15 — proven best: ~40 us, VGPR 120, no spills)
#define LOADT(KA, KB, BV, JT) do {                                             \
    int _j0 = (JT) * 64;                                                       \
    _Pragma("unroll")                                                          \
    for (int _s = 0; _s < 4; _s++) {                                           \
        const unsigned short* _kr = Kp + (long)(_j0 + _s * 16 + c) * 64 + g * 8; \
        KA[_s] = *(const short8*)(_kr);                                        \
        KB[_s] = *(const short8*)(_kr + 32);                                   \
    }                                                                          \
    const unsigned short* _bp = Bt + ((JT) << 10) + lane * 16;                 \
    BV[0] = *(const short8*)(_bp);                                             \
    BV[1] = *(const short8*)(_bp + 8);                                         \
} while (0)

#define BODY(KA, KB, BV, JT) do {                                             \
    int _j0 = (JT) * 64;                                                      \
    f32x4 _s[4];                                                              \
    _Pragma("unroll")                                                         \
    for (int _sub = 0; _sub < 4; _sub++) {                                    \
        _s[_sub] = __builtin_amdgcn_mfma_f32_16x16x32_bf16(KA[_sub], q0, zero, 0, 0, 0); \
        _s[_sub] = __builtin_amdgcn_mfma_f32_16x16x32_bf16(KB[_sub], q1, _s[_sub], 0, 0, 0); \
    }                                                                         \
    short8 _v0[4], _v1[4];                                                    \
    _Pragma("unroll")                                                         \
    for (int _dd = 0; _dd < 4; _dd++) {                                       \
        const unsigned short* _vb = Vp + (long)(_dd * 16 + c) * 1024 + _j0 + g * 8; \
        _v0[_dd] = *(const short8*)(_vb);                                     \
        _v1[_dd] = *(const short8*)(_vb + 32);                                \
    }                                                                         \
    unsigned int _P0[4], _P1[4];                                              \
    _Pragma("unroll")                                                         \
    for (int _sub = 0; _sub < 4; _sub++) {                                    \
        float _pe[4];                                                         \
        _Pragma("unroll")                                                     \
        for (int _r = 0; _r < 4; _r++) {                                      \
            int _idx = _sub * 4 + _r;                                         \
            float _ss = _s[_sub][_r] +                                        \
                ((_idx < 8) ? bf2f((unsigned short)BV[0][_idx])               \
                            : bf2f((unsigned short)BV[1][_idx - 8]));         \
            if ((JT) == nj - 1 && _j0 + _sub * 16 + g * 4 + _r > i0 + c)      \
                _ss = -1e9f;                                                  \
            _pe[_r] = exp2f(__builtin_fmaf(_ss, LOG2E, -8.0f * LOG2E));       \
            l += _pe[_r];                                                     \
        }                                                                     \
        asm("v_cvt_pk_bf16_f32 %0, %1, %2" : "=v"(_P0[_sub]) : "v"(_pe[0]), "v"(_pe[1])); \
        asm("v_cvt_pk_bf16_f32 %0, %1, %2" : "=v"(_P1[_sub]) : "v"(_pe[2]), "v"(_pe[3])); \
    }                                                                         \
    _Pragma("unroll")                                                         \
    for (int _ch = 0; _ch < 2; _ch++) {                                       \
        unsigned int _a0 = (unsigned int)__shfl((int)_P0[_ch * 2],     srcA); \
        unsigned int _a1 = (unsigned int)__shfl((int)_P0[_ch * 2 + 1], srcA); \
        unsigned int _b0 = (unsigned int)__shfl((int)_P1[_ch * 2],     srcA); \
        unsigned int _b1 = (unsigned int)__shfl((int)_P1[_ch * 2 + 1], srcA); \
        unsigned int _c0 = (unsigned int)__shfl((int)_P0[_ch * 2],     srcB); \
        unsigned int _c1 = (unsigned int)__shfl((int)_P0[_ch * 2 + 1], srcB); \
        unsigned int _d0 = (unsigned int)__shfl((int)_P1[_ch * 2],     srcB); \
        unsigned int _d1 = (unsigned int)__shfl((int)_P1[_ch * 2 + 1], srcB); \
        union { unsigned int u[4]; short8 s8; } _pb;                          \
        _pb.u[0] = sel ? _a1 : _a0;                                           \
        _pb.u[1] = sel ? _b1 : _b0;                                           \
        _pb.u[2] = sel ? _c1 : _c0;                                           \
        _pb.u[3] = sel ? _d1 : _d0;                                           \
        _Pragma("unroll")                                                     \
        for (int _dd = 0; _dd < 4; _dd++)                                     \
            o[_dd] = __builtin_amdgcn_mfma_f32_16x16x32_bf16(                 \
                (_ch == 0) ? _v0[_dd] : _v1[_dd], _pb.s8, o[_dd], 0, 0, 0);   \
    }                                                                         \
} while (0)

__global__ __launch_bounds__(256) void k_attn(
    const unsigned short* __restrict__ Qs, const unsigned short* __restrict__ Ks,
    const unsigned short* __restrict__ VTs, const unsigned short* __restrict__ biasg,
    unsigned short* __restrict__ Os) {
    // per-wave 4672B: oc 64x17 f32 [0,4352) + lc 64 f32 [4352,4608) + pad
    __shared__ char smem[4 * 4672];
    int bid = blockIdx.x;
    int it = 63 - (bid >> 5);          // heavy stripes dispatched first
    int bh = bid & 31;
    int b = bh >> 4, h = bh & 15;
    int w = threadIdx.x >> 6;
    int lane = threadIdx.x & 63;
    int g = lane >> 4, c = lane & 15;
    int i0 = it * 16;
    int srcA = ((lane >> 4) & 1) * 32 + c;   // P-exchange sources
    int srcB = srcA + 16;
    int sel  = (lane >> 5) & 1;

    char* wbase = smem + w * 4672;

    long plane = ((long)bh) << 16;
    const unsigned short* Qp = Qs + plane;
    const unsigned short* Kp = Ks + plane;
    const unsigned short* Vp = VTs + plane;             // [64 d][1024 j]
    const unsigned short* Bt = biasg + (((long)bh * 64 + it) << 14);

    short8 q0 = *(const short8*)(Qp + (long)(i0 + c) * 64 + g * 8);
    short8 q1 = *(const short8*)(Qp + (long)(i0 + c) * 64 + 32 + g * 8);

    f32x4 zero = {0.f, 0.f, 0.f, 0.f};
    f32x4 o[4]; o[0] = zero; o[1] = zero; o[2] = zero; o[3] = zero;
    float l = 0.f;

    int nj = (it >> 2) + 1;            // 64-col tiles
    short8 kaA[4], kbA[4], bvA[2];
    short8 kaB[4], kbB[4], bvB[2];
    if (w < nj) LOADT(kaA, kbA, bvA, w);
    for (int jt = w; jt < nj; jt += 8) {
        if (jt + 4 < nj) LOADT(kaB, kbB, bvB, jt + 4);
        BODY(kaA, kbA, bvA, jt);
        if (jt + 4 < nj) {
            if (jt + 8 < nj) LOADT(kaA, kbA, bvA, jt + 8);
            BODY(kaB, kbB, bvB, jt + 4);
        }
    }
    // ---- cross-wave combine: plain sums ----
    float* oc = (float*)wbase;                 // [64][17]
    float* lc = (float*)(wbase + 4352);        // [64]
    #pragma unroll
    for (int db = 0; db < 4; db++)
        #pragma unroll
        for (int r = 0; r < 4; r++)
            oc[lane * 17 + db * 4 + r] = o[db][r];
    lc[lane] = l;
    __syncthreads();

    {
        int db = w;                             // wave w stores d-block w
        float lv = 0.f;
        #pragma unroll
        for (int ww = 0; ww < 4; ww++)
            lv += ((const float*)(smem + ww * 4672 + 4352))[lane];
        lv += __shfl_xor(lv, 16);
        lv += __shfl_xor(lv, 32);
        float linv = 1.0f / lv;
        float ov[4];
        #pragma unroll
        for (int r = 0; r < 4; r++) {
            float s = 0.f;
            #pragma unroll
            for (int ww = 0; ww < 4; ww++)
                s += ((const float*)(smem + ww * 4672))[lane * 17 + db * 4 + r];
            ov[r] = s;
        }
        int i = i0 + c;
        unsigned short* op = Os + ((long)(b * 1024 + i)) * 1024 + h * 64 + db * 16 + g * 4;
        ushort4 o4;
        o4.x = f2bf(ov[0] * linv); o4.y = f2bf(ov[1] * linv);
        o4.z = f2bf(ov[2] * linv); o4.w = f2bf(ov[3] * linv);
        *(ushort4*)op = o4;
    }
}

// ------------------------------- launch ---------------------------------------
extern "C" void kernel_launch(void* const* d_in, const int* in_sizes, int n_in,
                              void* d_out, int out_size, void* d_ws, size_t ws_size,
                              hipStream_t stream) {
    const float* x     = (const float*)d_in[0];
    const float* Wq    = (const float*)d_in[1];
    const float* Wk    = (const float*)d_in[2];
    const float* Wv    = (const float*)d_in[3];
    const float* Wo    = (const float*)d_in[4];
    const float* Eidx  = (const float*)d_in[5];
    const float* Ebar  = (const float*)d_in[6];
    const float* Epos  = (const float*)d_in[7];
    const float* Eoct  = (const float*)d_in[8];
    const float* Esemi = (const float*)d_in[9];
    const int* barm    = (const int*)d_in[10];
    const int* posm    = (const int*)d_in[11];
    const int* octm    = (const int*)d_in[12];
    const int* semim   = (const int*)d_in[13];
    float* outf = (float*)d_out;

    unsigned short* w = (unsigned short*)d_ws;
    unsigned short* XB   = w;                   // 2M el
    unsigned short* WQB  = w + 2097152;         // 1M el each
    unsigned short* WKB  = w + 3145728;
    unsigned short* WVB  = w + 4194304;
    unsigned short* WOB  = w + 5242880;
    unsigned short* QS   = w + 6291456;         // (b,h,n,d)
    unsigned short* KS   = w + 8388608;
    unsigned short* VTS  = w + 10485760;        // (b,h,d,n)
    unsigned short* OS   = w + 12582912;        // (b,n,h*d)
    unsigned short* BIAS = w + 14680064;        // 32M el, swapped frag tiles

    k_prep<<<7232, 256, 0, stream>>>(x, Wq, Wk, Wv, Wo, w,
                                     Eidx, Ebar, Epos, Eoct, Esemi,
                                     barm, posm, octm, semim, BIAS);
    k_gemm<<<dim3(16, 16, 3), 256, 0, stream>>>(XB, WQB, WKB, WVB,
                                                QS, KS, VTS, nullptr, -1);
    k_attn<<<2048, 256, 0, stream>>>(QS, KS, VTS, BIAS, OS);
    k_gemm<<<dim3(16, 16, 1), 256, 0, stream>>>(OS, WOB, WOB, WOB,
                                                QS, KS, VTS, outf, 3);
}

// Round 22
// 100.359 us; speedup vs baseline: 1.4094x; 1.0288x over previous
//
#include <hip/hip_runtime.h>
#include <cstdint>
#include <math.h>

typedef __attribute__((ext_vector_type(8))) short short8;
typedef __attribute__((ext_vector_type(4))) float f32x4;

#define LOG2E 1.44269504088896340736f

static __device__ __forceinline__ float bf2f(unsigned short u) {
    union { unsigned int i; float f; } v; v.i = ((unsigned int)u) << 16; return v.f;
}
static __device__ __forceinline__ unsigned short f2bf(float f) {
    union { float f; unsigned int i; } v; v.f = f;
    unsigned int r = v.i + 0x7FFF + ((v.i >> 16) & 1);
    return (unsigned short)(r >> 16);
}

// ---------------- K1: fused prep = bias(1088 blocks first) + convert(6144) ----
// (unchanged from round 15 — validated; bias in swapped-QK C-layout)
__global__ __launch_bounds__(256) void k_prep(
    const float* __restrict__ x, const float* __restrict__ wq,
    const float* __restrict__ wk, const float* __restrict__ wv,
    const float* __restrict__ wo, unsigned short* __restrict__ dstconv,
    const float* __restrict__ Eidx, const float* __restrict__ Ebar,
    const float* __restrict__ Epos, const float* __restrict__ Eoct,
    const float* __restrict__ Esemi,
    const int* __restrict__ barm, const int* __restrict__ posm,
    const int* __restrict__ octm, const int* __restrict__ semim,
    unsigned short* __restrict__ biasg) {
    __shared__ float2 t2[8 * 233];
    __shared__ int    pk[16 * 65];

    if (blockIdx.x >= 1088) {
        long t = (long)(blockIdx.x - 1088) * 256 + threadIdx.x;
        long base = t * 4;
        const long NX = 2097152, NW = 1048576;
        const float* src; long off;
        if (base < NX)            { src = x;  off = base; }
        else if (base < NX + NW)  { src = wq; off = base - NX; }
        else if (base < NX + 2*NW){ src = wk; off = base - NX - NW; }
        else if (base < NX + 3*NW){ src = wv; off = base - NX - 2*NW; }
        else                      { src = wo; off = base - NX - 3*NW; }
        float4 v = *(const float4*)(src + off);
        ushort4 o;
        o.x = f2bf(v.x); o.y = f2bf(v.y); o.z = f2bf(v.z); o.w = f2bf(v.w);
        *(ushort4*)(dstconv + base) = o;
        return;
    }
    int fid = blockIdx.x;
    int b = (fid >= 544) ? 1 : 0;
    int f = fid - b * 544;
    int ti, tj;
    if (f >= 480) { int rr = f - 480; ti = 60 + (rr >> 4); tj = rr & 15; }
    else {
        int g = (int)(0.5f * (sqrtf(1.0f + 2.0f * (float)f) - 1.0f));
        while (2 * (g + 1) * (g + 2) <= f) g++;
        while (2 * g * (g + 1) > f) g--;
        int rr = f - 2 * g * (g + 1);
        int q = rr / (g + 1);
        ti = g * 4 + q;
        tj = rr - q * (g + 1);
    }
    int i0 = ti * 16, j0 = tj * 64;

    int t = threadIdx.x;
    int rel_lo = i0 - j0 - 63; if (rel_lo < 0) rel_lo = 0;

    for (int idx = t; idx < 231 * 8; idx += 256) {
        int s = idx >> 3, h2 = idx & 7;
        float va, vb;
        if (s < 80) {
            int src = rel_lo + s; if (src > 1023) src = 1023;
            va = Eidx[src * 16 + h2]; vb = Eidx[src * 16 + h2 + 8];
        } else if (s < 97)  { va = Ebar[(s - 80) * 16 + h2];  vb = Ebar[(s - 80) * 16 + h2 + 8]; }
        else if (s < 193)   { va = Epos[(s - 97) * 16 + h2];  vb = Epos[(s - 97) * 16 + h2 + 8]; }
        else if (s < 218)   { va = Eoct[(s - 193) * 16 + h2]; vb = Eoct[(s - 193) * 16 + h2 + 8]; }
        else                { va = Esemi[(s - 218) * 16 + h2]; vb = Esemi[(s - 218) * 16 + h2 + 8]; }
        t2[h2 * 233 + s] = make_float2(va, vb);
    }
    #pragma unroll
    for (int cc = 0; cc < 4; cc++) {
        int cell = t + cc * 256;
        int i = i0 + (cell >> 6), j = j0 + (cell & 63);
        long ij = ((long)b << 20) + ((long)i << 10) + j;
        int v = (barm[ij] + 1) | ((posm[ij] + 1) << 5) |
                ((octm[ij] + 1) << 12) | ((semim[ij] + 1) << 17);
        pk[(cell >> 6) * 65 + (cell & 63)] = v;
    }
    __syncthreads();

    int lane = t & 63, q = t & 15, G = (t >> 4) & 3, hq = t >> 6;
    int base_rel = (i0 + q) - j0 - rel_lo;
    const float2* TA = &t2[hq * 233];
    const float2* TB = &t2[(hq + 4) * 233];
    long tbase = ((((long)(b * 16) * 64 + ti) * 16 + tj) << 10) + lane * 16;
    #pragma unroll
    for (int sub = 0; sub < 4; sub++) {
        ushort4 o0, o1, o2, o3;
        #pragma unroll
        for (int rr = 0; rr < 4; rr++) {
            int key = sub * 16 + G * 4 + rr;
            int p = pk[q * 65 + key];
            int sr = base_rel - key; if (sr < 0) sr = 0;
            float2 a0 = TA[sr];
            float2 a1 = TA[80  + (p & 31)];
            float2 a2 = TA[97  + ((p >> 5)  & 127)];
            float2 a3 = TA[193 + ((p >> 12) & 31)];
            float2 a4 = TA[218 + ((p >> 17) & 15)];
            float2 b0 = TB[sr];
            float2 b1 = TB[80  + (p & 31)];
            float2 b2 = TB[97  + ((p >> 5)  & 127)];
            float2 b3 = TB[193 + ((p >> 12) & 31)];
            float2 b4 = TB[218 + ((p >> 17) & 15)];
            float xA = a0.x + a1.x + a2.x + a3.x + a4.x;
            float yA = a0.y + a1.y + a2.y + a3.y + a4.y;
            float xB = b0.x + b1.x + b2.x + b3.x + b4.x;
            float yB = b0.y + b1.y + b2.y + b3.y + b4.y;
            ((unsigned short*)&o0)[rr] = f2bf(xA * 0.125f);
            ((unsigned short*)&o1)[rr] = f2bf(xB * 0.125f);
            ((unsigned short*)&o2)[rr] = f2bf(yA * 0.125f);
            ((unsigned short*)&o3)[rr] = f2bf(yB * 0.125f);
        }
        *(ushort4*)(biasg + tbase + ((long)hq        << 20) + sub * 4) = o0;
        *(ushort4*)(biasg + tbase + ((long)(hq + 4)  << 20) + sub * 4) = o1;
        *(ushort4*)(biasg + tbase + ((long)(hq + 8)  << 20) + sub * 4) = o2;
        *(ushort4*)(biasg + tbase + ((long)(hq + 12) << 20) + sub * 4) = o3;
    }
}

// ---------------- K3/K5: bf16 GEMM, 128x64 tile, global_load_lds --------------
// (unchanged from round 13/14 — validated)
__global__ __launch_bounds__(256) void k_gemm(
    const unsigned short* __restrict__ A,
    const unsigned short* __restrict__ B0, const unsigned short* __restrict__ B1,
    const unsigned short* __restrict__ B2,
    unsigned short* __restrict__ qd, unsigned short* __restrict__ kd,
    unsigned short* __restrict__ vtd, float* __restrict__ outf, int mode) {
    __shared__ unsigned short As[128 * 64];
    __shared__ unsigned short Bs[64 * 64];
    int md = (mode < 0) ? (int)blockIdx.z : mode;
    const unsigned short* B = (md == 1) ? B1 : (md == 2) ? B2 : B0;
    int m0 = blockIdx.x * 128, n0 = blockIdx.y * 64;
    int t = threadIdx.x;
    int w = t >> 6, lane = t & 63, g = lane >> 4, c = lane & 15;
    int wr = w >> 1, wc = w & 1;
    const int K = 1024;
    f32x4 zero = {0.f, 0.f, 0.f, 0.f};
    f32x4 acc[4][2];
    #pragma unroll
    for (int m = 0; m < 4; m++)
        #pragma unroll
        for (int n = 0; n < 2; n++) acc[m][n] = zero;

    int srow = w * 8 + (lane >> 3);
    int scol = (lane & 7) * 8;
    for (int k0 = 0; k0 < K; k0 += 64) {
        __syncthreads();
        #pragma unroll
        for (int qq = 0; qq < 4; qq++) {
            int row = qq * 32 + srow;
            __builtin_amdgcn_global_load_lds(
                (const __attribute__((address_space(1))) unsigned int*)(A + (long)(m0 + row) * K + k0 + scol),
                (__attribute__((address_space(3))) unsigned int*)&As[(qq * 32 + w * 8) * 64],
                16, 0, 0);
        }
        #pragma unroll
        for (int qq = 0; qq < 2; qq++) {
            int row = qq * 32 + srow;
            __builtin_amdgcn_global_load_lds(
                (const __attribute__((address_space(1))) unsigned int*)(B + (long)(n0 + row) * K + k0 + scol),
                (__attribute__((address_space(3))) unsigned int*)&Bs[(qq * 32 + w * 8) * 64],
                16, 0, 0);
        }
        __syncthreads();
        #pragma unroll
        for (int kk = 0; kk < 2; kk++) {
            short8 a[4], bb[2];
            #pragma unroll
            for (int m = 0; m < 4; m++)
                a[m] = *(const short8*)&As[(wr * 64 + m * 16 + c) * 64 + kk * 32 + g * 8];
            #pragma unroll
            for (int n = 0; n < 2; n++)
                bb[n] = *(const short8*)&Bs[(wc * 32 + n * 16 + c) * 64 + kk * 32 + g * 8];
            #pragma unroll
            for (int m = 0; m < 4; m++)
                #pragma unroll
                for (int n = 0; n < 2; n++)
                    acc[m][n] = __builtin_amdgcn_mfma_f32_16x16x32_bf16(a[m], bb[n], acc[m][n], 0, 0, 0);
        }
    }

    if (md <= 1) {
        unsigned short* dst = (md == 0) ? qd : kd;
        float scale = (md == 0) ? 0.125f : 1.0f;
        #pragma unroll
        for (int m = 0; m < 4; m++) {
            #pragma unroll
            for (int r = 0; r < 4; r++) {
                int mm = m0 + wr * 64 + m * 16 + g * 4 + r;
                int bb2 = mm >> 10, ii = mm & 1023;
                #pragma unroll
                for (int n = 0; n < 2; n++) {
                    int nn = n0 + wc * 32 + n * 16 + c;
                    int hh = nn >> 6, dd = nn & 63;
                    dst[(((long)(bb2 * 16 + hh) << 10) + ii) * 64 + dd] = f2bf(acc[m][n][r] * scale);
                }
            }
        }
    } else if (md == 2) {
        #pragma unroll
        for (int m = 0; m < 4; m++) {
            int mm0 = m0 + wr * 64 + m * 16 + g * 4;
            int bb2 = mm0 >> 10, ii = mm0 & 1023;
            #pragma unroll
            for (int n = 0; n < 2; n++) {
                int nn = n0 + wc * 32 + n * 16 + c;
                int hh = nn >> 6, dd = nn & 63;
                ushort4 pkv;
                pkv.x = f2bf(acc[m][n][0]); pkv.y = f2bf(acc[m][n][1]);
                pkv.z = f2bf(acc[m][n][2]); pkv.w = f2bf(acc[m][n][3]);
                *(ushort4*)&vtd[(((long)(bb2 * 16 + hh) << 6) + dd) * 1024 + ii] = pkv;
            }
        }
    } else {
        #pragma unroll
        for (int m = 0; m < 4; m++) {
            #pragma unroll
            for (int r = 0; r < 4; r++) {
                long mm = m0 + wr * 64 + m * 16 + g * 4 + r;
                #pragma unroll
                for (int n = 0; n < 2; n++) {
                    int nn = n0 + wc * 32 + n * 16 + c;
                    outf[mm * 1024 + nn] = acc[m][n][r];
                }
            }
        }
    }
}

// ---------------- K4: flash attention, wave-per-i-tile, shared K/V reads ------
// grid 512 = 16 itg-groups x 32 (b,h); wave w owns i-tile 4*itg+w. All 4 waves
// have IDENTICAL nj = itg+1 and loop the same jt range in near-lockstep ->
// K/V loads are same-address across waves (L1/L2 served once, ~4x less L2/L3
// traffic). Each wave owns complete rows: l reduces with 2 shfl_xor, O written
// directly. NO LDS, no syncthreads, no combine. Block pairing: first 256 bids
// itg 15..8, second 256 itg 0..7 -> per-CU-slot sum uniform (17 units).
#define LOADT(KA, KB, BV, JT) do {                                             \
    int _j0 = (JT) * 64;                                                       \
    _Pragma("unroll")                                                          \
    for (int _s = 0; _s < 4; _s++) {                                           \
        const unsigned short* _kr = Kp + (long)(_j0 + _s * 16 + c) * 64 + g * 8; \
        KA[_s] = *(const short8*)(_kr);                                        \
        KB[_s] = *(const short8*)(_kr + 32);                                   \
    }                                                                          \
    const unsigned short* _bp = Bt + ((JT) << 10) + lane * 16;                 \
    BV[0] = *(const short8*)(_bp);                                             \
    BV[1] = *(const short8*)(_bp + 8);                                         \
} while (0)

#define BODY(KA, KB, BV, JT) do {                                             \
    int _j0 = (JT) * 64;                                                      \
    f32x4 _s[4];                                                              \
    _Pragma("unroll")                                                         \
    for (int _sub = 0; _sub < 4; _sub++) {                                    \
        _s[_sub] = __builtin_amdgcn_mfma_f32_16x16x32_bf16(KA[_sub], q0, zero, 0, 0, 0); \
        _s[_sub] = __builtin_amdgcn_mfma_f32_16x16x32_bf16(KB[_sub], q1, _s[_sub], 0, 0, 0); \
    }                                                                         \
    short8 _v0[4], _v1[4];                                                    \
    _Pragma("unroll")                                                         \
    for (int _dd = 0; _dd < 4; _dd++) {                                       \
        const unsigned short* _vb = Vp + (long)(_dd * 16 + c) * 1024 + _j0 + g * 8; \
        _v0[_dd] = *(const short8*)(_vb);                                     \
        _v1[_dd] = *(const short8*)(_vb + 32);                                \
    }                                                                         \
    unsigned int _P0[4], _P1[4];                                              \
    _Pragma("unroll")                                                         \
    for (int _sub = 0; _sub < 4; _sub++) {                                    \
        float _pe[4];                                                         \
        _Pragma("unroll")                                                     \
        for (int _r = 0; _r < 4; _r++) {                                      \
            int _idx = _sub * 4 + _r;                                         \
            float _ss = _s[_sub][_r] +                                        \
                ((_idx < 8) ? bf2f((unsigned short)BV[0][_idx])               \
                            : bf2f((unsigned short)BV[1][_idx - 8]));         \
            if ((JT) == nj - 1 && _j0 + _sub * 16 + g * 4 + _r > i0 + c)      \
                _ss = -1e9f;                                                  \
            _pe[_r] = exp2f(__builtin_fmaf(_ss, LOG2E, -8.0f * LOG2E));       \
            l += _pe[_r];                                                     \
        }                                                                     \
        asm("v_cvt_pk_bf16_f32 %0, %1, %2" : "=v"(_P0[_sub]) : "v"(_pe[0]), "v"(_pe[1])); \
        asm("v_cvt_pk_bf16_f32 %0, %1, %2" : "=v"(_P1[_sub]) : "v"(_pe[2]), "v"(_pe[3])); \
    }                                                                         \
    _Pragma("unroll")                                                         \
    for (int _ch = 0; _ch < 2; _ch++) {                                       \
        unsigned int _a0 = (unsigned int)__shfl((int)_P0[_ch * 2],     srcA); \
        unsigned int _a1 = (unsigned int)__shfl((int)_P0[_ch * 2 + 1], srcA); \
        unsigned int _b0 = (unsigned int)__shfl((int)_P1[_ch * 2],     srcA); \
        unsigned int _b1 = (unsigned int)__shfl((int)_P1[_ch * 2 + 1], srcA); \
        unsigned int _c0 = (unsigned int)__shfl((int)_P0[_ch * 2],     srcB); \
        unsigned int _c1 = (unsigned int)__shfl((int)_P0[_ch * 2 + 1], srcB); \
        unsigned int _d0 = (unsigned int)__shfl((int)_P1[_ch * 2],     srcB); \
        unsigned int _d1 = (unsigned int)__shfl((int)_P1[_ch * 2 + 1], srcB); \
        union { unsigned int u[4]; short8 s8; } _pb;                          \
        _pb.u[0] = sel ? _a1 : _a0;                                           \
        _pb.u[1] = sel ? _b1 : _b0;                                           \
        _pb.u[2] = sel ? _c1 : _c0;                                           \
        _pb.u[3] = sel ? _d1 : _d0;                                           \
        _Pragma("unroll")                                                     \
        for (int _dd = 0; _dd < 4; _dd++)                                     \
            o[_dd] = __builtin_amdgcn_mfma_f32_16x16x32_bf16(                 \
                (_ch == 0) ? _v0[_dd] : _v1[_dd], _pb.s8, o[_dd], 0, 0, 0);   \
    }                                                                         \
} while (0)

__global__ __launch_bounds__(256) void k_attn(
    const unsigned short* __restrict__ Qs, const unsigned short* __restrict__ Ks,
    const unsigned short* __restrict__ VTs, const unsigned short* __restrict__ biasg,
    unsigned short* __restrict__ Os) {
    int bid = blockIdx.x;
    int itg = (bid < 256) ? (15 - (bid >> 5)) : ((bid - 256) >> 5);
    int bh = bid & 31;
    int b = bh >> 4, h = bh & 15;
    int w = threadIdx.x >> 6;
    int lane = threadIdx.x & 63;
    int g = lane >> 4, c = lane & 15;
    int it = itg * 4 + w;              // wave w owns i-tile 4*itg+w
    int i0 = it * 16;
    int srcA = ((lane >> 4) & 1) * 32 + c;   // P-exchange sources
    int srcB = srcA + 16;
    int sel  = (lane >> 5) & 1;

    long plane = ((long)bh) << 16;
    const unsigned short* Qp = Qs + plane;
    const unsigned short* Kp = Ks + plane;
    const unsigned short* Vp = VTs + plane;             // [64 d][1024 j]
    const unsigned short* Bt = biasg + (((long)bh * 64 + it) << 14);

    short8 q0 = *(const short8*)(Qp + (long)(i0 + c) * 64 + g * 8);
    short8 q1 = *(const short8*)(Qp + (long)(i0 + c) * 64 + 32 + g * 8);

    f32x4 zero = {0.f, 0.f, 0.f, 0.f};
    f32x4 o[4]; o[0] = zero; o[1] = zero; o[2] = zero; o[3] = zero;
    float l = 0.f;

    int nj = itg + 1;                  // identical for all 4 waves
    short8 kaA[4], kbA[4], bvA[2];
    short8 kaB[4], kbB[4], bvB[2];
    LOADT(kaA, kbA, bvA, 0);
    for (int jt = 0; jt < nj; jt += 2) {
        if (jt + 1 < nj) LOADT(kaB, kbB, bvB, jt + 1);
        BODY(kaA, kbA, bvA, jt);
        if (jt + 1 < nj) {
            if (jt + 2 < nj) LOADT(kaA, kbA, bvA, jt + 2);
            BODY(kaB, kbB, bvB, jt + 1);
        }
    }
    // ---- epilogue: per-wave row-complete; reduce l over g-groups via shfl ----
    float lv = l;
    lv += __shfl_xor(lv, 16);
    lv += __shfl_xor(lv, 32);
    float linv = 1.0f / lv;
    int i = i0 + c;
    unsigned short* op = Os + ((long)(b * 1024 + i)) * 1024 + h * 64 + g * 4;
    #pragma unroll
    for (int db = 0; db < 4; db++) {
        ushort4 o4;
        o4.x = f2bf(o[db][0] * linv); o4.y = f2bf(o[db][1] * linv);
        o4.z = f2bf(o[db][2] * linv); o4.w = f2bf(o[db][3] * linv);
        *(ushort4*)(op + db * 16) = o4;
    }
}

// ------------------------------- launch ---------------------------------------
extern "C" void kernel_launch(void* const* d_in, const int* in_sizes, int n_in,
                              void* d_out, int out_size, void* d_ws, size_t ws_size,
                              hipStream_t stream) {
    const float* x     = (const float*)d_in[0];
    const float* Wq    = (const float*)d_in[1];
    const float* Wk    = (const float*)d_in[2];
    const float* Wv    = (const float*)d_in[3];
    const float* Wo    = (const float*)d_in[4];
    const float* Eidx  = (const float*)d_in[5];
    const float* Ebar  = (const float*)d_in[6];
    const float* Epos  = (const float*)d_in[7];
    const float* Eoct  = (const float*)d_in[8];
    const float* Esemi = (const float*)d_in[9];
    const int* barm    = (const int*)d_in[10];
    const int* posm    = (const int*)d_in[11];
    const int* octm    = (const int*)d_in[12];
    const int* semim   = (const int*)d_in[13];
    float* outf = (float*)d_out;

    unsigned short* w = (unsigned short*)d_ws;
    unsigned short* XB   = w;                   // 2M el
    unsigned short* WQB  = w + 2097152;         // 1M el each
    unsigned short* WKB  = w + 3145728;
    unsigned short* WVB  = w + 4194304;
    unsigned short* WOB  = w + 5242880;
    unsigned short* QS   = w + 6291456;         // (b,h,n,d)
    unsigned short* KS   = w + 8388608;
    unsigned short* VTS  = w + 10485760;        // (b,h,d,n)
    unsigned short* OS   = w + 12582912;        // (b,n,h*d)
    unsigned short* BIAS = w + 14680064;        // 32M el, swapped frag tiles

    k_prep<<<7232, 256, 0, stream>>>(x, Wq, Wk, Wv, Wo, w,
                                     Eidx, Ebar, Epos, Eoct, Esemi,
                                     barm, posm, octm, semim, BIAS);
    k_gemm<<<dim3(16, 16, 3), 256, 0, stream>>>(XB, WQB, WKB, WVB,
                                                QS, KS, VTS, nullptr, -1);
    k_attn<<<512, 256, 0, stream>>>(QS, KS, VTS, BIAS, OS);
    k_gemm<<<dim3(16, 16, 1), 256, 0, stream>>>(OS, WOB, WOB, WOB,
                                                QS, KS, VTS, outf, 3);
}